// Round 1
// baseline (697.696 us; speedup 1.0000x reference)
//
#include <hip/hip_runtime.h>
#include <hip/hip_bf16.h>

#define NTOK 4096
#define CDIM 256
#define HDIM 1024
#define NEXP 32
#define MT   64
#define LDX  264   // XH row stride (shorts): 528B = 132 banks -> 2-way max on frag reads
#define LDW  40    // Wb row stride (shorts): 80B = 20 banks -> 2-way max

typedef __bf16 bf16x8 __attribute__((ext_vector_type(8)));
typedef float  f32x4  __attribute__((ext_vector_type(4)));

__device__ __forceinline__ unsigned short f2bf(float f) {
    __hip_bfloat16 h = __float2bfloat16(f);
    return __builtin_bit_cast(unsigned short, h);
}

__device__ __forceinline__ float gelu_tanh(float v) {
    float c = 0.7978845608028654f * (v + 0.044715f * v * v * v);
    return 0.5f * v * (1.0f + tanhf(c));
}

// ---------------- router: softmax gate + top-3 + dense router_weights ----------------
__global__ void k_router(const float* __restrict__ x, const float* __restrict__ gW,
                         const float* __restrict__ gb, const float* __restrict__ eb,
                         float* __restrict__ rw, int* __restrict__ cnt,
                         int* __restrict__ idx4, float* __restrict__ w4)
{
    int n = blockIdx.x;
    int l = threadIdx.x;
    __shared__ float sb[32];
    const float* xr = x + (size_t)n * CDIM;
    if (l < 31) {
        float acc = 0.f;
        const float* wc = gW + l;
        #pragma unroll 8
        for (int k = 0; k < CDIM; ++k) acc = fmaf(xr[k], wc[k * 31], acc);
        sb[l] = acc + gb[l];
    }
    __syncthreads();
    if (l == 0) {
        float mx = sb[0];
        for (int e2 = 1; e2 < 31; ++e2) mx = fmaxf(mx, sb[e2]);
        float p[31]; float s = 0.f;
        #pragma unroll
        for (int e2 = 0; e2 < 31; ++e2) { p[e2] = expf(sb[e2] - mx); s += p[e2]; }
        float inv = 1.f / s;
        float bi[31];
        #pragma unroll
        for (int e2 = 0; e2 < 31; ++e2) bi[e2] = p[e2] * inv + eb[e2];
        // top-3, ties -> lower index (strict > matches lax.top_k stability)
        int i0 = 0, i1 = 0, i2 = 0;
        float v0 = -1e30f, v1 = -1e30f, v2 = -1e30f;
        #pragma unroll
        for (int e2 = 0; e2 < 31; ++e2) {
            float v = bi[e2];
            if (v > v0)      { v2 = v1; i2 = i1; v1 = v0; i1 = i0; v0 = v; i0 = e2; }
            else if (v > v1) { v2 = v1; i2 = i1; v1 = v;  i1 = e2; }
            else if (v > v2) { v2 = v;  i2 = e2; }
        }
        float invs = 0.75f / (v0 + v1 + v2);
        float w0 = v0 * invs, w1_ = v1 * invs, w2_ = v2 * invs;
        float* r = rw + (size_t)n * NEXP;
        #pragma unroll
        for (int e2 = 0; e2 < NEXP; ++e2) r[e2] = 0.f;
        r[0] = 0.25f; r[i0 + 1] = w0; r[i1 + 1] = w1_; r[i2 + 1] = w2_;
        idx4[n*4+0] = 0;      idx4[n*4+1] = i0 + 1; idx4[n*4+2] = i1 + 1; idx4[n*4+3] = i2 + 1;
        w4[n*4+0]  = 0.25f;   w4[n*4+1]  = w0;      w4[n*4+2]  = w1_;     w4[n*4+3]  = w2_;
        atomicAdd(&cnt[0], 1); atomicAdd(&cnt[i0+1], 1);
        atomicAdd(&cnt[i1+1], 1); atomicAdd(&cnt[i2+1], 1);
    }
}

__global__ void k_scan(const int* __restrict__ cnt, int* __restrict__ off) {
    if (threadIdx.x == 0) {
        int a = 0;
        for (int e = 0; e < NEXP; ++e) { off[e] = a; a += cnt[e]; }
    }
}

__global__ void k_scatter(const int* __restrict__ idx4, const int* __restrict__ off,
                          int* __restrict__ cur, int* __restrict__ list)
{
    int n = blockIdx.x * blockDim.x + threadIdx.x;
    if (n >= NTOK) return;
    #pragma unroll
    for (int s = 0; s < 4; ++s) {
        int e = idx4[n*4 + s];
        int pos = atomicAdd(&cur[e], 1);
        list[off[e] + pos] = n*4 + s;
    }
}

// ---------------- grouped sparse expert FFN with bf16 MFMA ----------------
__launch_bounds__(256, 2)
__global__ void k_moe(const float* __restrict__ x, const float* __restrict__ W1,
                      const float* __restrict__ b1, const float* __restrict__ W2,
                      const float* __restrict__ b2, const int* __restrict__ cnt,
                      const int* __restrict__ off, const int* __restrict__ list,
                      const float* __restrict__ w4, float* __restrict__ out)
{
    const int e = blockIdx.y;
    const int tile = blockIdx.x;
    const int count = cnt[e];
    if (tile * MT >= count) return;

    __shared__ __align__(16) unsigned short XH[MT * LDX];   // X then H (per chunk)
    __shared__ __align__(16) unsigned short Wb[CDIM * LDW]; // transposed weight chunk [n][k]
    __shared__ int   toks[MT];
    __shared__ float wgts[MT];

    const int tid = threadIdx.x;
    const int base = off[e] + tile * MT;
    const int nvalid = min(MT, count - tile * MT);
    if (tid < MT) {
        if (tid < nvalid) { int a = list[base + tid]; toks[tid] = a >> 2; wgts[tid] = w4[a]; }
        else              { toks[tid] = 0; wgts[tid] = 0.f; }
    }
    __syncthreads();

    const int w = tid >> 6, l = tid & 63, q = l >> 4, m16 = l & 15;
    const float* W1e = W1 + (size_t)e * CDIM * HDIM;
    const float* W2e = W2 + (size_t)e * HDIM * CDIM;

    const f32x4 fzero = {0.f, 0.f, 0.f, 0.f};
    f32x4 oacc[4][4];
    #pragma unroll
    for (int i = 0; i < 4; ++i)
        #pragma unroll
        for (int j = 0; j < 4; ++j) oacc[i][j] = fzero;

    const int xrow = tid >> 2, xcb = (tid & 3) * 64;

    for (int nc = 0; nc < 4; ++nc) {
        __syncthreads();  // previous chunk's readers of XH are done
        // (re)load gathered X tile -> bf16 LDS
        {
            const float* xr = x + (size_t)toks[xrow] * CDIM + xcb;
            unsigned short* dst = XH + xrow * LDX + xcb;
            #pragma unroll
            for (int j2 = 0; j2 < 64; j2 += 4) {
                float4 v = *(const float4*)(xr + j2);
                ushort4 u; u.x = f2bf(v.x); u.y = f2bf(v.y); u.z = f2bf(v.z); u.w = f2bf(v.w);
                *(ushort4*)(dst + j2) = u;
            }
        }

        f32x4 hacc[4][4];
        #pragma unroll
        for (int i = 0; i < 4; ++i)
            #pragma unroll
            for (int j = 0; j < 4; ++j) hacc[i][j] = fzero;

        const int hc0 = nc * 256;
        // ---- stage 1: H = gelu(X @ W1_chunk + b1) ----
        for (int ks = 0; ks < 8; ++ks) {
            __syncthreads();
            {
                const int k0 = ks * 32;
                #pragma unroll
                for (int kp = 0; kp < 16; ++kp) {
                    float f0 = W1e[(size_t)(k0 + 2*kp    ) * HDIM + hc0 + tid];
                    float f1 = W1e[(size_t)(k0 + 2*kp + 1) * HDIM + hc0 + tid];
                    unsigned pv = (unsigned)f2bf(f0) | ((unsigned)f2bf(f1) << 16);
                    *(unsigned*)(Wb + tid * LDW + 2*kp) = pv;
                }
            }
            __syncthreads();
            bf16x8 a[4], b[4];
            #pragma unroll
            for (int ai = 0; ai < 4; ++ai)
                a[ai] = *(const bf16x8*)(XH + (16*ai + m16) * LDX + ks*32 + q*8);
            #pragma unroll
            for (int bj = 0; bj < 4; ++bj)
                b[bj] = *(const bf16x8*)(Wb + (64*w + 16*bj + m16) * LDW + q*8);
            #pragma unroll
            for (int ai = 0; ai < 4; ++ai)
                #pragma unroll
                for (int bj = 0; bj < 4; ++bj)
                    hacc[ai][bj] = __builtin_amdgcn_mfma_f32_16x16x32_bf16(a[ai], b[bj], hacc[ai][bj], 0, 0, 0);
        }
        __syncthreads();  // all waves done reading X before overwrite with H
        // bias + gelu, store H into XH (wave writes cols [64w,64w+64) of all rows)
        #pragma unroll
        for (int bj = 0; bj < 4; ++bj) {
            int colc = 64*w + 16*bj + m16;
            float bv = b1[e * HDIM + hc0 + colc];
            #pragma unroll
            for (int ai = 0; ai < 4; ++ai)
                #pragma unroll
                for (int r = 0; r < 4; ++r) {
                    int row = 16*ai + 4*q + r;
                    XH[row * LDX + colc] = f2bf(gelu_tanh(hacc[ai][bj][r] + bv));
                }
        }
        // ---- stage 2: O += H @ W2_chunk ----
        for (int ks = 0; ks < 8; ++ks) {
            __syncthreads();
            {
                const int k0 = ks * 32;
                #pragma unroll
                for (int kp = 0; kp < 16; ++kp) {
                    float f0 = W2e[(size_t)(hc0 + k0 + 2*kp    ) * CDIM + tid];
                    float f1 = W2e[(size_t)(hc0 + k0 + 2*kp + 1) * CDIM + tid];
                    unsigned pv = (unsigned)f2bf(f0) | ((unsigned)f2bf(f1) << 16);
                    *(unsigned*)(Wb + tid * LDW + 2*kp) = pv;
                }
            }
            __syncthreads();
            bf16x8 a[4], b[4];
            #pragma unroll
            for (int ai = 0; ai < 4; ++ai)
                a[ai] = *(const bf16x8*)(XH + (16*ai + m16) * LDX + ks*32 + q*8);
            #pragma unroll
            for (int bj = 0; bj < 4; ++bj)
                b[bj] = *(const bf16x8*)(Wb + (64*w + 16*bj + m16) * LDW + q*8);
            #pragma unroll
            for (int ai = 0; ai < 4; ++ai)
                #pragma unroll
                for (int bj = 0; bj < 4; ++bj)
                    oacc[ai][bj] = __builtin_amdgcn_mfma_f32_16x16x32_bf16(a[ai], b[bj], oacc[ai][bj], 0, 0, 0);
        }
    }

    // epilogue: add b2, scale by gate weight, accumulate into out
    #pragma unroll
    for (int bj = 0; bj < 4; ++bj) {
        int col = 64*w + 16*bj + m16;
        float b2v = b2[e * CDIM + col];
        #pragma unroll
        for (int ai = 0; ai < 4; ++ai)
            #pragma unroll
            for (int r = 0; r < 4; ++r) {
                int row = 16*ai + 4*q + r;
                float wv = wgts[row];
                if (wv != 0.f)
                    atomicAdd(out + (size_t)toks[row] * CDIM + col, (oacc[ai][bj][r] + b2v) * wv);
            }
    }
}

extern "C" void kernel_launch(void* const* d_in, const int* in_sizes, int n_in,
                              void* d_out, int out_size, void* d_ws, size_t ws_size,
                              hipStream_t stream)
{
    const float* x  = (const float*)d_in[0];
    const float* gW = (const float*)d_in[1];
    const float* gb = (const float*)d_in[2];
    const float* eb = (const float*)d_in[3];
    const float* W1 = (const float*)d_in[4];
    const float* b1 = (const float*)d_in[5];
    const float* W2 = (const float*)d_in[6];
    const float* b2 = (const float*)d_in[7];
    float* out = (float*)d_out;
    float* rw  = out + (size_t)NTOK * CDIM;   // second output: router_weights [N, 32]

    int*   cnt  = (int*)d_ws;          // 32
    int*   cur  = cnt + 32;            // 32
    int*   off  = cnt + 64;            // 32
    int*   idx4 = cnt + 128;           // 4096*4 ints
    float* w4   = (float*)(idx4 + NTOK * 4);  // 4096*4 floats
    int*   list = (int*)(w4 + NTOK * 4);      // 16384 ints

    hipMemsetAsync(d_ws, 0, 512, stream);                                  // cnt + cur
    hipMemsetAsync(d_out, 0, (size_t)NTOK * CDIM * sizeof(float), stream); // out accum region

    k_router<<<NTOK, 64, 0, stream>>>(x, gW, gb, eb, rw, cnt, idx4, w4);
    k_scan<<<1, 64, 0, stream>>>(cnt, off);
    k_scatter<<<NTOK / 256, 256, 0, stream>>>(idx4, off, cur, list);
    k_moe<<<dim3(64, NEXP), 256, 0, stream>>>(x, W1, b1, W2, b2, cnt, off, list, w4, out);
}

// Round 2
// 570.712 us; speedup vs baseline: 1.2225x; 1.2225x over previous
//
#include <hip/hip_runtime.h>
#include <hip/hip_bf16.h>

#define NTOK 4096
#define CDIM 256
#define HDIM 1024
#define NEXP 32
#define MT   64
#define LDX  264   // XH row stride in shorts; 528 B = 16B-aligned rows, 2-way max conflicts

typedef __bf16 bf16x8 __attribute__((ext_vector_type(8)));
typedef float  f32x4  __attribute__((ext_vector_type(4)));

__device__ __forceinline__ unsigned short f2bf(float f) {
    __hip_bfloat16 h = __float2bfloat16(f);
    return __builtin_bit_cast(unsigned short, h);
}

__device__ __forceinline__ float gelu_tanh(float v) {
    float c = 0.7978845608028654f * (v + 0.044715f * v * v * v);
    return 0.5f * v * (1.0f + tanhf(c));
}

// ---------------- convert x -> bf16 ----------------
__global__ void k_cvt_x(const float* __restrict__ x, unsigned short* __restrict__ xb) {
    int i = (blockIdx.x * 256 + threadIdx.x) * 4;
    float4 v = *(const float4*)(x + i);
    ushort4 u; u.x = f2bf(v.x); u.y = f2bf(v.y); u.z = f2bf(v.z); u.w = f2bf(v.w);
    *(ushort4*)(xb + i) = u;
}

// ---------------- pre-shuffle W1/W2 -> bf16 MFMA B-fragment order ----------------
// W1s tile id gw = e*512 + hb*8 + kb   (hb: 64 n-blocks of 16 over HDIM, kb: 8 k-blocks of 32 over CDIM)
// W2s tile id g2 = e*512 + nb*32 + kb  (nb: 16 n-blocks of 16 over CDIM, kb: 32 k-blocks of 32 over HDIM)
// frag(lane l, j=0..7) = W[k = kb*32 + (l>>4)*8 + j][n = *b*16 + (l&15)]
__global__ void k_cvt_w(const float* __restrict__ W1, const float* __restrict__ W2,
                        unsigned short* __restrict__ W1s, unsigned short* __restrict__ W2s)
{
    const int gw = (blockIdx.x * 256 + threadIdx.x) >> 6;
    const int l = threadIdx.x & 63, q = l >> 4, m16 = l & 15;
    unsigned short t[8];
    uint4 u;
    if (gw < 16384) {
        const int e = gw >> 9, hb = (gw >> 3) & 63, kb = gw & 7;
        const float* src = W1 + ((size_t)e * CDIM + kb * 32 + q * 8) * HDIM + hb * 16 + m16;
        #pragma unroll
        for (int j = 0; j < 8; ++j) t[j] = f2bf(src[(size_t)j * HDIM]);
        u.x = (unsigned)t[0] | ((unsigned)t[1] << 16);
        u.y = (unsigned)t[2] | ((unsigned)t[3] << 16);
        u.z = (unsigned)t[4] | ((unsigned)t[5] << 16);
        u.w = (unsigned)t[6] | ((unsigned)t[7] << 16);
        *(uint4*)(W1s + (size_t)gw * 512 + l * 8) = u;
    } else {
        const int g2 = gw - 16384;
        const int e = g2 >> 9, nb = (g2 >> 5) & 15, kb = g2 & 31;
        const float* src = W2 + ((size_t)e * HDIM + kb * 32 + q * 8) * CDIM + nb * 16 + m16;
        #pragma unroll
        for (int j = 0; j < 8; ++j) t[j] = f2bf(src[(size_t)j * CDIM]);
        u.x = (unsigned)t[0] | ((unsigned)t[1] << 16);
        u.y = (unsigned)t[2] | ((unsigned)t[3] << 16);
        u.z = (unsigned)t[4] | ((unsigned)t[5] << 16);
        u.w = (unsigned)t[6] | ((unsigned)t[7] << 16);
        *(uint4*)(W2s + (size_t)g2 * 512 + l * 8) = u;
    }
}

// ---------------- router: wave-parallel softmax + top-3 ----------------
__global__ void k_router(const float* __restrict__ x, const float* __restrict__ gW,
                         const float* __restrict__ gb, const float* __restrict__ eb,
                         float* __restrict__ rw, int* __restrict__ cnt,
                         int* __restrict__ idx4, float* __restrict__ w4)
{
    const int l = threadIdx.x & 63;
    const int n = blockIdx.x * 4 + (threadIdx.x >> 6);
    const float* xr = x + (size_t)n * CDIM;
    float logit = -1e30f;
    if (l < 31) {
        float acc = 0.f;
        #pragma unroll 8
        for (int k = 0; k < CDIM; ++k) acc = fmaf(xr[k], gW[k * 31 + l], acc);
        logit = acc + gb[l];
    }
    float mx = logit;
    #pragma unroll
    for (int o = 32; o; o >>= 1) mx = fmaxf(mx, __shfl_xor(mx, o));
    float p = (l < 31) ? expf(logit - mx) : 0.f;
    float s = p;
    #pragma unroll
    for (int o = 32; o; o >>= 1) s += __shfl_xor(s, o);
    float v = (l < 31) ? p / s + eb[l] : -1e30f;
    float tv[3]; int ti[3];
    #pragma unroll
    for (int r = 0; r < 3; ++r) {
        float m = v;
        #pragma unroll
        for (int o = 32; o; o >>= 1) m = fmaxf(m, __shfl_xor(m, o));
        unsigned long long msk = __ballot(v == m);
        int src = __ffsll(msk) - 1;           // ties -> lowest index, matches lax.top_k
        tv[r] = m; ti[r] = src;
        if (l == src) v = -1e30f;
    }
    float invs = 0.75f / (tv[0] + tv[1] + tv[2]);
    float w0 = tv[0] * invs, w1 = tv[1] * invs, w2 = tv[2] * invs;
    if (l < 32) {
        float val = (l == 0) ? 0.25f : 0.f;
        if (l == ti[0] + 1) val = w0;
        if (l == ti[1] + 1) val = w1;
        if (l == ti[2] + 1) val = w2;
        rw[(size_t)n * NEXP + l] = val;
    }
    if (l == 0) {
        idx4[n*4+0] = 0;      idx4[n*4+1] = ti[0]+1; idx4[n*4+2] = ti[1]+1; idx4[n*4+3] = ti[2]+1;
        w4[n*4+0]  = 0.25f;   w4[n*4+1]  = w0;       w4[n*4+2]  = w1;       w4[n*4+3]  = w2;
        atomicAdd(&cnt[0], 1);        atomicAdd(&cnt[ti[0]+1], 1);
        atomicAdd(&cnt[ti[1]+1], 1);  atomicAdd(&cnt[ti[2]+1], 1);
    }
}

__global__ void k_scan(const int* __restrict__ cnt, int* __restrict__ off) {
    if (threadIdx.x == 0) {
        int a = 0;
        for (int e = 0; e < NEXP; ++e) { off[e] = a; a += cnt[e]; }
    }
}

__global__ void k_scatter(const int* __restrict__ idx4, const int* __restrict__ off,
                          int* __restrict__ cur, int* __restrict__ list)
{
    int n = blockIdx.x * blockDim.x + threadIdx.x;
    if (n >= NTOK) return;
    #pragma unroll
    for (int s = 0; s < 4; ++s) {
        int e = idx4[n*4 + s];
        int pos = atomicAdd(&cur[e], 1);
        list[off[e] + pos] = n*4 + s;
    }
}

// ---------------- grouped sparse expert FFN: direct-global B-frags, barrier-light ----------------
__launch_bounds__(256, 2)
__global__ void k_moe(const unsigned short* __restrict__ xb,
                      const unsigned short* __restrict__ W1s,
                      const float* __restrict__ b1,
                      const unsigned short* __restrict__ W2s,
                      const float* __restrict__ b2,
                      const int* __restrict__ cnt, const int* __restrict__ off,
                      const int* __restrict__ list, const float* __restrict__ w4,
                      float* __restrict__ out)
{
    const int e = blockIdx.y;
    const int tile = blockIdx.x;
    const int count = cnt[e];
    if (tile * MT >= count) return;

    __shared__ __align__(16) unsigned short XH[MT * LDX];
    __shared__ int   toks[MT];
    __shared__ float wgts[MT];

    const int tid = threadIdx.x;
    const int base = off[e] + tile * MT;
    const int nvalid = min(MT, count - tile * MT);
    if (tid < MT) {
        if (tid < nvalid) { int a = list[base + tid]; toks[tid] = a >> 2; wgts[tid] = w4[a]; }
        else              { toks[tid] = 0; wgts[tid] = 0.f; }
    }

    const int w = tid >> 6, l = tid & 63, q = l >> 4, m16 = l & 15;
    const int xrow = tid >> 2, xcb = (tid & 3) * 64;

    const f32x4 fzero = {0.f, 0.f, 0.f, 0.f};
    f32x4 oacc[4][4];
    #pragma unroll
    for (int i = 0; i < 4; ++i)
        #pragma unroll
        for (int j = 0; j < 4; ++j) oacc[i][j] = fzero;

    for (int nc = 0; nc < 4; ++nc) {
        __syncthreads();   // prev chunk's stage-2 readers done (and toks[] visible at nc==0)
        // restage gathered X tile (bf16, pure copy)
        {
            const unsigned short* xr = xb + (size_t)toks[xrow] * CDIM + xcb;
            unsigned short* dst = XH + xrow * LDX + xcb;
            #pragma unroll
            for (int j = 0; j < 64; j += 8)
                *(uint4*)(dst + j) = *(const uint4*)(xr + j);
        }
        __syncthreads();

        f32x4 hacc[4][4];
        #pragma unroll
        for (int i = 0; i < 4; ++i)
            #pragma unroll
            for (int j = 0; j < 4; ++j) hacc[i][j] = fzero;

        // ---- stage 1: H = gelu(X @ W1_chunk + b1); B-frags straight from global ----
        const unsigned short* w1base = W1s + ((size_t)(e * 64 + nc * 16 + 4 * w) * 8) * 512 + l * 8;
        #pragma unroll 2
        for (int ks = 0; ks < 8; ++ks) {
            bf16x8 a[4], b[4];
            #pragma unroll
            for (int bj = 0; bj < 4; ++bj)
                b[bj] = *(const bf16x8*)(w1base + bj * 4096 + ks * 512);
            #pragma unroll
            for (int ai = 0; ai < 4; ++ai)
                a[ai] = *(const bf16x8*)(XH + (16*ai + m16) * LDX + ks*32 + q*8);
            #pragma unroll
            for (int ai = 0; ai < 4; ++ai)
                #pragma unroll
                for (int bj = 0; bj < 4; ++bj)
                    hacc[ai][bj] = __builtin_amdgcn_mfma_f32_16x16x32_bf16(a[ai], b[bj], hacc[ai][bj], 0, 0, 0);
        }
        __syncthreads();   // all X reads done before overwriting XH with H

        const int hc0 = nc * 256;
        #pragma unroll
        for (int bj = 0; bj < 4; ++bj) {
            int colc = 64*w + 16*bj + m16;
            float bv = b1[e * HDIM + hc0 + colc];
            #pragma unroll
            for (int ai = 0; ai < 4; ++ai)
                #pragma unroll
                for (int r = 0; r < 4; ++r) {
                    int row = 16*ai + 4*q + r;
                    XH[row * LDX + colc] = f2bf(gelu_tanh(hacc[ai][bj][r] + bv));
                }
        }
        __syncthreads();   // H visible to all waves

        // ---- stage 2: O += H @ W2_chunk ----
        const unsigned short* w2base = W2s + ((size_t)(e * 16 + 4 * w) * 32 + nc * 8) * 512 + l * 8;
        #pragma unroll 2
        for (int ks = 0; ks < 8; ++ks) {
            bf16x8 a[4], b[4];
            #pragma unroll
            for (int bj = 0; bj < 4; ++bj)
                b[bj] = *(const bf16x8*)(w2base + bj * 16384 + ks * 512);
            #pragma unroll
            for (int ai = 0; ai < 4; ++ai)
                a[ai] = *(const bf16x8*)(XH + (16*ai + m16) * LDX + ks*32 + q*8);
            #pragma unroll
            for (int ai = 0; ai < 4; ++ai)
                #pragma unroll
                for (int bj = 0; bj < 4; ++bj)
                    oacc[ai][bj] = __builtin_amdgcn_mfma_f32_16x16x32_bf16(a[ai], b[bj], oacc[ai][bj], 0, 0, 0);
        }
    }

    // epilogue: +b2, scale by gate weight, atomic accumulate
    #pragma unroll
    for (int bj = 0; bj < 4; ++bj) {
        int col = 64*w + 16*bj + m16;
        float b2v = b2[e * CDIM + col];
        #pragma unroll
        for (int ai = 0; ai < 4; ++ai)
            #pragma unroll
            for (int r = 0; r < 4; ++r) {
                int row = 16*ai + 4*q + r;
                float wv = wgts[row];
                if (wv != 0.f)
                    atomicAdd(out + (size_t)toks[row] * CDIM + col, (oacc[ai][bj][r] + b2v) * wv);
            }
    }
}

extern "C" void kernel_launch(void* const* d_in, const int* in_sizes, int n_in,
                              void* d_out, int out_size, void* d_ws, size_t ws_size,
                              hipStream_t stream)
{
    const float* x  = (const float*)d_in[0];
    const float* gW = (const float*)d_in[1];
    const float* gb = (const float*)d_in[2];
    const float* eb = (const float*)d_in[3];
    const float* W1 = (const float*)d_in[4];
    const float* b1 = (const float*)d_in[5];
    const float* W2 = (const float*)d_in[6];
    const float* b2 = (const float*)d_in[7];
    float* out = (float*)d_out;
    float* rw  = out + (size_t)NTOK * CDIM;   // second output: router_weights [N, 32]

    char* p = (char*)d_ws;
    int*   cnt  = (int*)p;                    // 32
    int*   cur  = cnt + 32;                   // 32
    int*   off  = cnt + 64;                   // 32
    int*   idx4 = cnt + 128;                  // 16384 ints
    float* w4   = (float*)(idx4 + NTOK * 4);  // 16384 floats
    int*   list = (int*)(w4 + NTOK * 4);      // 16384 ints
    unsigned short* xbuf = (unsigned short*)(p + (1 << 20));         // 2 MB
    unsigned short* W1s  = xbuf + (size_t)NTOK * CDIM;               // 16.78 MB
    unsigned short* W2s  = W1s + (size_t)NEXP * CDIM * HDIM;         // 16.78 MB

    hipMemsetAsync(d_ws, 0, 512, stream);                                  // cnt + cur + off
    hipMemsetAsync(d_out, 0, (size_t)NTOK * CDIM * sizeof(float), stream); // out accum region

    k_cvt_x<<<NTOK * CDIM / 1024, 256, 0, stream>>>(x, xbuf);
    k_cvt_w<<<8192, 256, 0, stream>>>(W1, W2, W1s, W2s);
    k_router<<<NTOK / 4, 256, 0, stream>>>(x, gW, gb, eb, rw, cnt, idx4, w4);
    k_scan<<<1, 64, 0, stream>>>(cnt, off);
    k_scatter<<<NTOK / 256, 256, 0, stream>>>(idx4, off, cur, list);
    k_moe<<<dim3(64, NEXP), 256, 0, stream>>>(xbuf, W1s, b1, W2s, b2, cnt, off, list, w4, out);
}

// Round 3
// 470.547 us; speedup vs baseline: 1.4827x; 1.2129x over previous
//
#include <hip/hip_runtime.h>
#include <hip/hip_bf16.h>

#define NTOK 4096
#define CDIM 256
#define HDIM 1024
#define NEXP 32
#define MT   64
#define LDX  264   // XH row stride in shorts

typedef __bf16 bf16x8 __attribute__((ext_vector_type(8)));
typedef float  f32x4  __attribute__((ext_vector_type(4)));

__device__ __forceinline__ unsigned short f2bf(float f) {
    __hip_bfloat16 h = __float2bfloat16(f);
    return __builtin_bit_cast(unsigned short, h);
}

__device__ __forceinline__ float gelu_tanh(float v) {
    float c = 0.7978845608028654f * (v + 0.044715f * v * v * v);
    return 0.5f * v * (1.0f + tanhf(c));
}

// ---------------- pre-shuffle W1/W2 -> bf16 MFMA B-fragment order (+ zero cur) ----------------
// W1s tile id gw = e*512 + hb*8 + kb   (hb: 64 n-blocks of 16 over HDIM, kb: 8 k-blocks of 32 over CDIM)
// W2s tile id g2 = e*512 + nb*32 + kb  (nb: 16 n-blocks of 16 over CDIM, kb: 32 k-blocks of 32 over HDIM)
// frag(lane l, j=0..7) = W[k = kb*32 + (l>>4)*8 + j][n = *b*16 + (l&15)]
__global__ void k_cvt_w(const float* __restrict__ W1, const float* __restrict__ W2,
                        unsigned short* __restrict__ W1s, unsigned short* __restrict__ W2s,
                        int* __restrict__ cur)
{
    if (blockIdx.x == 0 && threadIdx.x < NEXP) cur[threadIdx.x] = 0;
    const int gw = (blockIdx.x * 256 + threadIdx.x) >> 6;
    const int l = threadIdx.x & 63, q = l >> 4, m16 = l & 15;
    unsigned short t[8];
    uint4 u;
    if (gw < 16384) {
        const int e = gw >> 9, hb = (gw >> 3) & 63, kb = gw & 7;
        const float* src = W1 + ((size_t)e * CDIM + kb * 32 + q * 8) * HDIM + hb * 16 + m16;
        #pragma unroll
        for (int j = 0; j < 8; ++j) t[j] = f2bf(src[(size_t)j * HDIM]);
        u.x = (unsigned)t[0] | ((unsigned)t[1] << 16);
        u.y = (unsigned)t[2] | ((unsigned)t[3] << 16);
        u.z = (unsigned)t[4] | ((unsigned)t[5] << 16);
        u.w = (unsigned)t[6] | ((unsigned)t[7] << 16);
        *(uint4*)(W1s + (size_t)gw * 512 + l * 8) = u;
    } else {
        const int g2 = gw - 16384;
        const int e = g2 >> 9, nb = (g2 >> 5) & 15, kb = g2 & 31;
        const float* src = W2 + ((size_t)e * HDIM + kb * 32 + q * 8) * CDIM + nb * 16 + m16;
        #pragma unroll
        for (int j = 0; j < 8; ++j) t[j] = f2bf(src[(size_t)j * CDIM]);
        u.x = (unsigned)t[0] | ((unsigned)t[1] << 16);
        u.y = (unsigned)t[2] | ((unsigned)t[3] << 16);
        u.z = (unsigned)t[4] | ((unsigned)t[5] << 16);
        u.w = (unsigned)t[6] | ((unsigned)t[7] << 16);
        *(uint4*)(W2s + (size_t)g2 * 512 + l * 8) = u;
    }
}

// ---------------- router: wave-parallel softmax + top-3, fused x->bf16, direct bucket scatter ----------------
__global__ void k_router(const float* __restrict__ x, const float* __restrict__ gW,
                         const float* __restrict__ gb, const float* __restrict__ eb,
                         float* __restrict__ rw, unsigned short* __restrict__ xb,
                         int* __restrict__ cur, int* __restrict__ list, float* __restrict__ w4)
{
    const int l = threadIdx.x & 63;
    const int wv = threadIdx.x >> 6;
    const int n = blockIdx.x * 4 + wv;
    __shared__ float xs[4][256];
    const float* xr = x + (size_t)n * CDIM;
    // stage row to LDS + convert to bf16
    float4 v = *(const float4*)(xr + l * 4);
    ushort4 u; u.x = f2bf(v.x); u.y = f2bf(v.y); u.z = f2bf(v.z); u.w = f2bf(v.w);
    *(ushort4*)(xb + (size_t)n * CDIM + l * 4) = u;
    *(float4*)(&xs[wv][l * 4]) = v;
    __syncthreads();

    float logit = -1e30f;
    if (l < 31) {
        float acc = 0.f;
        #pragma unroll 8
        for (int k = 0; k < CDIM; ++k) acc = fmaf(xs[wv][k], gW[k * 31 + l], acc);
        logit = acc + gb[l];
    }
    float mx = logit;
    #pragma unroll
    for (int o = 32; o; o >>= 1) mx = fmaxf(mx, __shfl_xor(mx, o));
    float p = (l < 31) ? expf(logit - mx) : 0.f;
    float s = p;
    #pragma unroll
    for (int o = 32; o; o >>= 1) s += __shfl_xor(s, o);
    float bv = (l < 31) ? p / s + eb[l] : -1e30f;
    float tv[3]; int ti[3];
    #pragma unroll
    for (int r = 0; r < 3; ++r) {
        float m = bv;
        #pragma unroll
        for (int o = 32; o; o >>= 1) m = fmaxf(m, __shfl_xor(m, o));
        unsigned long long msk = __ballot(bv == m);
        int src = __ffsll(msk) - 1;           // ties -> lowest index, matches lax.top_k
        tv[r] = m; ti[r] = src;
        if (l == src) bv = -1e30f;
    }
    float invs = 0.75f / (tv[0] + tv[1] + tv[2]);
    float w0 = tv[0] * invs, w1 = tv[1] * invs, w2 = tv[2] * invs;
    if (l < 32) {
        float val = (l == 0) ? 0.25f : 0.f;
        if (l == ti[0] + 1) val = w0;
        if (l == ti[1] + 1) val = w1;
        if (l == ti[2] + 1) val = w2;
        rw[(size_t)n * NEXP + l] = val;
    }
    if (l == 0) {
        w4[n*4+0] = 0.25f; w4[n*4+1] = w0; w4[n*4+2] = w1; w4[n*4+3] = w2;
        int e1 = ti[0] + 1, e2 = ti[1] + 1, e3 = ti[2] + 1;
        int p0 = atomicAdd(&cur[0], 1);  list[p0]             = n * 4 + 0;
        int p1 = atomicAdd(&cur[e1], 1); list[e1 * NTOK + p1] = n * 4 + 1;
        int p2 = atomicAdd(&cur[e2], 1); list[e2 * NTOK + p2] = n * 4 + 2;
        int p3 = atomicAdd(&cur[e3], 1); list[e3 * NTOK + p3] = n * 4 + 3;
    }
}

// ---------------- grouped sparse expert FFN: one hidden-chunk per block ----------------
__launch_bounds__(256, 4)
__global__ void k_moe(const unsigned short* __restrict__ xb,
                      const unsigned short* __restrict__ W1s,
                      const float* __restrict__ b1,
                      const unsigned short* __restrict__ W2s,
                      const float* __restrict__ b2,
                      const int* __restrict__ cur, const int* __restrict__ list,
                      const float* __restrict__ w4, float* __restrict__ out)
{
    const int e = blockIdx.y;
    const int nc = blockIdx.z;
    const int tile = blockIdx.x;
    const int count = cur[e];
    if (tile * MT >= count) return;

    __shared__ __align__(16) unsigned short XH[MT * LDX];
    __shared__ int   stoks[MT];
    __shared__ float wgts[MT];

    const int tid = threadIdx.x, w = tid >> 6, l = tid & 63, q = l >> 4, m16 = l & 15;
    const int base = e * NTOK + tile * MT;
    const int nvalid = min(MT, count - tile * MT);

    // prefetch stage-1 ks=0 B-frags (independent of everything below)
    const unsigned short* w1base = W1s + ((size_t)(e * 64 + nc * 16 + 4 * w) * 8) * 512 + l * 8;
    bf16x8 pb[4];
    #pragma unroll
    for (int bj = 0; bj < 4; ++bj) pb[bj] = *(const bf16x8*)(w1base + bj * 4096);

    if (tid < MT) {
        if (tid < nvalid) { int a = list[base + tid]; stoks[tid] = a >> 2; wgts[tid] = w4[a]; }
        else              { stoks[tid] = 0; wgts[tid] = 0.f; }
    }
    // stage gathered X tile (each thread resolves its row's token directly)
    {
        const int xrow = tid >> 2, xcb = (tid & 3) * 64;
        const int a = (xrow < nvalid) ? list[base + xrow] : 0;
        const unsigned short* xr = xb + (size_t)(a >> 2) * CDIM + xcb;
        unsigned short* dst = XH + xrow * LDX + xcb;
        #pragma unroll
        for (int j = 0; j < 64; j += 8)
            *(uint4*)(dst + j) = *(const uint4*)(xr + j);
    }
    __syncthreads();

    // ---- stage 1: H = gelu(X @ W1_chunk + b1) ----
    const f32x4 fzero = {0.f, 0.f, 0.f, 0.f};
    f32x4 hacc[4][4];
    #pragma unroll
    for (int i = 0; i < 4; ++i)
        #pragma unroll
        for (int j = 0; j < 4; ++j) hacc[i][j] = fzero;

    #pragma unroll 2
    for (int ks = 0; ks < 8; ++ks) {
        bf16x8 b[4], a[4];
        #pragma unroll
        for (int bj = 0; bj < 4; ++bj) b[bj] = pb[bj];
        const int ksn = (ks < 7) ? ks + 1 : 7;   // dead prefetch re-reads ks=7 (valid addr)
        #pragma unroll
        for (int bj = 0; bj < 4; ++bj) pb[bj] = *(const bf16x8*)(w1base + bj * 4096 + ksn * 512);
        #pragma unroll
        for (int ai = 0; ai < 4; ++ai)
            a[ai] = *(const bf16x8*)(XH + (16*ai + m16) * LDX + ks*32 + q*8);
        #pragma unroll
        for (int ai = 0; ai < 4; ++ai)
            #pragma unroll
            for (int bj = 0; bj < 4; ++bj)
                hacc[ai][bj] = __builtin_amdgcn_mfma_f32_16x16x32_bf16(a[ai], b[bj], hacc[ai][bj], 0, 0, 0);
    }
    __syncthreads();   // all X reads done before overwriting XH with H

    // prefetch stage-2 ks=0 B-frags, then write H
    const unsigned short* w2base = W2s + ((size_t)(e * 16 + 4 * w) * 32 + nc * 8) * 512 + l * 8;
    #pragma unroll
    for (int bj = 0; bj < 4; ++bj) pb[bj] = *(const bf16x8*)(w2base + bj * 16384);

    const int hc0 = nc * 256;
    #pragma unroll
    for (int bj = 0; bj < 4; ++bj) {
        int colc = 64*w + 16*bj + m16;
        float bv = b1[e * HDIM + hc0 + colc];
        #pragma unroll
        for (int ai = 0; ai < 4; ++ai)
            #pragma unroll
            for (int r = 0; r < 4; ++r) {
                int row = 16*ai + 4*q + r;
                XH[row * LDX + colc] = f2bf(gelu_tanh(hacc[ai][bj][r] + bv));
            }
    }
    __syncthreads();   // H visible to all waves

    // ---- stage 2: O = H @ W2_chunk ----
    f32x4 oacc[4][4];
    #pragma unroll
    for (int i = 0; i < 4; ++i)
        #pragma unroll
        for (int j = 0; j < 4; ++j) oacc[i][j] = fzero;

    #pragma unroll 2
    for (int ks = 0; ks < 8; ++ks) {
        bf16x8 b[4], a[4];
        #pragma unroll
        for (int bj = 0; bj < 4; ++bj) b[bj] = pb[bj];
        const int ksn = (ks < 7) ? ks + 1 : 7;
        #pragma unroll
        for (int bj = 0; bj < 4; ++bj) pb[bj] = *(const bf16x8*)(w2base + bj * 16384 + ksn * 512);
        #pragma unroll
        for (int ai = 0; ai < 4; ++ai)
            a[ai] = *(const bf16x8*)(XH + (16*ai + m16) * LDX + ks*32 + q*8);
        #pragma unroll
        for (int ai = 0; ai < 4; ++ai)
            #pragma unroll
            for (int bj = 0; bj < 4; ++bj)
                oacc[ai][bj] = __builtin_amdgcn_mfma_f32_16x16x32_bf16(a[ai], b[bj], oacc[ai][bj], 0, 0, 0);
    }

    // epilogue: +b2, scale by gate weight, atomic accumulate
    #pragma unroll
    for (int bj = 0; bj < 4; ++bj) {
        int col = 64*w + 16*bj + m16;
        float b2v = b2[e * CDIM + col];
        #pragma unroll
        for (int ai = 0; ai < 4; ++ai)
            #pragma unroll
            for (int r = 0; r < 4; ++r) {
                int row = 16*ai + 4*q + r;
                float wv = wgts[row];
                if (wv != 0.f)
                    atomicAdd(out + (size_t)stoks[row] * CDIM + col, (oacc[ai][bj][r] + b2v) * wv);
            }
    }
}

extern "C" void kernel_launch(void* const* d_in, const int* in_sizes, int n_in,
                              void* d_out, int out_size, void* d_ws, size_t ws_size,
                              hipStream_t stream)
{
    const float* x  = (const float*)d_in[0];
    const float* gW = (const float*)d_in[1];
    const float* gb = (const float*)d_in[2];
    const float* eb = (const float*)d_in[3];
    const float* W1 = (const float*)d_in[4];
    const float* b1 = (const float*)d_in[5];
    const float* W2 = (const float*)d_in[6];
    const float* b2 = (const float*)d_in[7];
    float* out = (float*)d_out;
    float* rw  = out + (size_t)NTOK * CDIM;   // second output: router_weights [N, 32]

    char* p = (char*)d_ws;
    int*   cur  = (int*)p;                           // 32 ints
    float* w4   = (float*)(p + 1024);                // 16384 floats
    int*   list = (int*)(p + 1024 + 65536);          // 32*4096 ints (bucketed)
    unsigned short* xbuf = (unsigned short*)(p + (1 << 20));   // 2 MB
    unsigned short* W1s  = xbuf + (size_t)NTOK * CDIM;         // 16.78 MB
    unsigned short* W2s  = W1s + (size_t)NEXP * CDIM * HDIM;   // 16.78 MB

    hipMemsetAsync(d_out, 0, (size_t)NTOK * CDIM * sizeof(float), stream); // out accum region

    k_cvt_w<<<8192, 256, 0, stream>>>(W1, W2, W1s, W2s, cur);
    k_router<<<NTOK / 4, 256, 0, stream>>>(x, gW, gb, eb, rw, xbuf, cur, list, w4);
    k_moe<<<dim3(64, NEXP, 4), 256, 0, stream>>>(xbuf, W1s, b1, W2s, b2, cur, list, w4, out);
}